// Round 5
// baseline (7016.018 us; speedup 1.0000x reference)
//
#include <hip/hip_runtime.h>
#include <hip/hip_bf16.h>

// ---------------------------------------------------------------------------
// LSTM_66675072303478: 2-layer LSTM (B=512,S=128,E=7,H=1024) + FC(1024->672)
//
// v16 = v15 (2924us best: v11 skeleton + zero-conflict XOR-swizzled LDS) with
// the k-loop sync restructured to counted-vmcnt raw barriers (T3/T4):
//  - v15 post-mortem: conflicts 0, FETCH at v11 floor, but ~12us/round of
//    stall remains. Cause: each of 48 k-iters issues global loads right
//    before __syncthreads(), which lowers with s_waitcnt vmcnt(0) -> full
//    L2/MALL latency (~250-400ns for EA-stored h lines) exposed per iter.
//  - Fix: per-iter sync becomes {ds_write; s_waitcnt lgkmcnt(0); raw
//    s_barrier} -- no vmcnt drain, loads stay in flight across barriers.
//    Register pipeline deepened to TWO in-flight load sets: load k-step j at
//    iter j-3, LDS-write at j-1 (compiler emits counted vmcnt(5): younger
//    set outstanding), consume at j. Issue->use = 2 iters >= MALL latency.
//  - Global access pattern/order is byte-identical to v15 (weights stay
//    L2-resident; h EA-store/3-slot/L1-inv scheme untouched). Outer
//    per-round __syncthreads() kept (EA stores must drain before flag inc).
//  - proven & kept: 4(m)x2(n) waves, wave tile 16x64, gate-interleaved
//    epilogue, fragment swizzle phys = row*128 + ((chunk^(row&7))<<4).
// ---------------------------------------------------------------------------

typedef __bf16 bf16x8 __attribute__((ext_vector_type(8)));
typedef float  f32x4  __attribute__((ext_vector_type(4)));

#define HSZ   (512 * 1024)  // one h buffer: 512 rows x 1024 cols (bf16)

__device__ __forceinline__ float sigm_f(float x) {
    x = fminf(30.f, fmaxf(-30.f, x));
    return 1.0f / (1.0f + __expf(-x));
}
__device__ __forceinline__ float tanh_f(float x) {
    x = fminf(30.f, fmaxf(-30.f, x));
    float e = __expf(-2.0f * x);
    return (1.0f - e) / (1.0f + e);
}

// n' = (j/16)*64 + g*16 + (j%16)  ->  original gate-major row g*1024 + j
__device__ __forceinline__ int perm_row(int np) {
    int g = (np >> 4) & 3;
    int j = ((np >> 6) << 4) | (np & 15);
    return g * 1024 + j;
}

// ---- relaxed-only flag ops (NO acquire/release -> no L2 inv/wb) ------------
__device__ __forceinline__ void spin_ge(const int* p, int target) {
    while (__hip_atomic_load(p, __ATOMIC_RELAXED, __HIP_MEMORY_SCOPE_AGENT) < target)
        __builtin_amdgcn_s_sleep(1);
}
__device__ __forceinline__ void signal_inc(int* p) {
    __hip_atomic_fetch_add(p, 1, __ATOMIC_RELAXED, __HIP_MEMORY_SCOPE_AGENT);
}
// L1-only invalidate (CU scope). Leaves L2/MALL intact; compiler fence.
__device__ __forceinline__ void inv_l1() {
    asm volatile("buffer_inv" ::: "memory");
}
// EA-point coherent dword store: bypasses L2s -> visible chip-wide.
__device__ __forceinline__ void store_ea(unsigned* p, unsigned v) {
    __hip_atomic_store(p, v, __ATOMIC_RELAXED, __HIP_MEMORY_SCOPE_AGENT);
}

// ---------------- weight prep kernels (run every call) ----------------------

__global__ void prep_w0(const float* __restrict__ Wh0, __bf16* __restrict__ W0p) {
    int idx = blockIdx.x * 256 + threadIdx.x;
    int np = idx >> 8, k4 = (idx & 255) << 2;
    int r = perm_row(np);
    float4 v = *(const float4*)(Wh0 + r * 1024 + k4);
    __bf16* o = W0p + np * 1024 + k4;
    o[0] = (__bf16)v.x; o[1] = (__bf16)v.y; o[2] = (__bf16)v.z; o[3] = (__bf16)v.w;
}

__global__ void prep_w1(const float* __restrict__ Wi1, const float* __restrict__ Wh1,
                        __bf16* __restrict__ W1p) {
    int idx = blockIdx.x * 256 + threadIdx.x;
    int np = idx >> 9, k4 = (idx & 511) << 2;
    int r = perm_row(np);
    const float* s = (k4 < 1024) ? (Wi1 + r * 1024 + k4) : (Wh1 + r * 1024 + (k4 - 1024));
    float4 v = *(const float4*)s;
    __bf16* o = W1p + np * 2048 + k4;
    o[0] = (__bf16)v.x; o[1] = (__bf16)v.y; o[2] = (__bf16)v.z; o[3] = (__bf16)v.w;
}

__global__ void prep_wfc(const float* __restrict__ Wfc, __bf16* __restrict__ Wfcp) {
    int idx = blockIdx.x * 256 + threadIdx.x;
    int n = idx >> 8, k4 = (idx & 255) << 2;
    __bf16* o = Wfcp + n * 1024 + k4;
    if (n < 672) {
        float4 v = *(const float4*)(Wfc + n * 1024 + k4);
        o[0] = (__bf16)v.x; o[1] = (__bf16)v.y; o[2] = (__bf16)v.z; o[3] = (__bf16)v.w;
    } else {
        o[0] = (__bf16)0.f; o[1] = (__bf16)0.f; o[2] = (__bf16)0.f; o[3] = (__bf16)0.f;
    }
}

__global__ void prep_small(const float* __restrict__ Wi0, const float* __restrict__ b0,
                           const float* __restrict__ b1,
                           float* __restrict__ Wi0p, float* __restrict__ b1p) {
    int np = blockIdx.x * 256 + threadIdx.x;
    int r = perm_row(np);
    float* o = Wi0p + np * 8;
    #pragma unroll
    for (int q = 0; q < 7; ++q) o[q] = Wi0[r * 7 + q];
    o[7] = b0[r];
    b1p[np] = b1[r];
}

// ---------------- fused pipelined K=1024 sub-loop (512 threads) -------------
// Tile 64x128, 8 waves in 4(m)x2(n), wave tile 16x64, BK=64, LDS dbuf.
// Two register load-sets in flight; per-iter sync = lgkmcnt(0) + raw
// s_barrier (NO vmcnt drain). Schedule: ld(k j) @ iter j-3, wr @ iter j-1
// (counted vmcnt: younger set outstanding), consume @ iter j.
// LDS layout: 128B rows, phys = row*128 + ((chunk ^ (row&7))<<4).

struct BRegs { uint4 a, b00, b01, b10, b11; };

template <bool D0, bool D1>
__device__ __forceinline__ void floop(const __bf16* __restrict__ abase,
                                      const __bf16* __restrict__ w0row,
                                      const __bf16* __restrict__ w1row,
                                      int tid,
                                      char* AldsB, char* B0ldsB, char* B1ldsB,
                                      f32x4 (&acc0)[4], f32x4 (&acc1)[4]) {
    const int a_r = tid >> 3;             // 0..63
    const int a_c = (tid & 7) << 3;       // 0..56 step 8 (16 B)
    const int b_r = tid >> 2;             // 0..127
    const int b_c = (tid & 3) << 4;       // 0,16,32,48 (2 x 16 B each)
    const int l  = tid & 63, w = tid >> 6;
    const int wm = w & 3,   wn = w >> 2;
    const int lj = l & 15,  lq = l >> 4;
    const int r7 = lj & 7;

    const __bf16* arw = abase + a_r * 1024 + a_c;

    // swizzled LDS byte offsets (writes)
    const int awr  = a_r * 128 + (((tid & 7) ^ (a_r & 7)) << 4);
    const int bwr0 = b_r * 128 + (((((tid & 3) << 1) | 0) ^ (b_r & 7)) << 4);
    const int bwr1 = b_r * 128 + (((((tid & 3) << 1) | 1) ^ (b_r & 7)) << 4);
    // swizzled chunk offsets (reads), chunk = (s<<2)|lq
    const int rc0 = ((lq     ) ^ r7) << 4;   // s = 0
    const int rc1 = ((lq | 4 ) ^ r7) << 4;   // s = 1

    BRegs s0, s1;

    auto ld = [&](BRegs& s, int k0) {
        s.a = *(const uint4*)(arw + k0);
        if (D0) {
            const __bf16* p = w0row + k0;
            s.b00 = *(const uint4*)(p);
            s.b01 = *(const uint4*)(p + 8);
        }
        if (D1) {
            const __bf16* p = w1row + k0;
            s.b10 = *(const uint4*)(p);
            s.b11 = *(const uint4*)(p + 8);
        }
    };
    auto wr = [&](const BRegs& s, int buf) {
        *(uint4*)(AldsB + buf * 8192 + awr) = s.a;
        if (D0) {
            char* Bl = B0ldsB + buf * 16384;
            *(uint4*)(Bl + bwr0) = s.b00;
            *(uint4*)(Bl + bwr1) = s.b01;
        }
        if (D1) {
            char* Bl = B1ldsB + buf * 16384;
            *(uint4*)(Bl + bwr0) = s.b10;
            *(uint4*)(Bl + bwr1) = s.b11;
        }
    };
    auto mm = [&](int bo) {
        const char* Ab  = AldsB  + (wm * 16 + lj) * 128 + bo * 8192;
        const char* B0b = B0ldsB + (wn * 64 + lj) * 128 + bo * 16384;
        const char* B1b = B1ldsB + (wn * 64 + lj) * 128 + bo * 16384;
        #pragma unroll
        for (int s = 0; s < 2; ++s) {
            const int rc = s ? rc1 : rc0;
            bf16x8 af = *(const bf16x8*)(Ab + rc);
            #pragma unroll
            for (int ni = 0; ni < 4; ++ni) {
                if (D0) {
                    bf16x8 b0 = *(const bf16x8*)(B0b + ni * 2048 + rc);
                    acc0[ni] = __builtin_amdgcn_mfma_f32_16x16x32_bf16(af, b0, acc0[ni], 0, 0, 0);
                }
                if (D1) {
                    bf16x8 b1 = *(const bf16x8*)(B1b + ni * 2048 + rc);
                    acc1[ni] = __builtin_amdgcn_mfma_f32_16x16x32_bf16(af, b1, acc1[ni], 0, 0, 0);
                }
            }
        }
    };

    // prologue: k0 -> buf0 (one vmcnt(0) here only); k1 -> s1, k2 -> s0
    ld(s0, 0);
    wr(s0, 0);
    ld(s1, 64);
    ld(s0, 128);
    asm volatile("s_waitcnt lgkmcnt(0)" ::: "memory");
    __builtin_amdgcn_s_barrier();

    for (int t = 0; t < 8; ++t) {
        // iter i = 2t (even): consume buf0; write k(i+1) from s1; load k(i+3)
        mm(0);
        if (2 * t + 1 < 16) wr(s1, 1);
        if (2 * t + 3 < 16) ld(s1, (2 * t + 3) * 64);
        asm volatile("s_waitcnt lgkmcnt(0)" ::: "memory");
        __builtin_amdgcn_s_barrier();
        // iter i = 2t+1 (odd): consume buf1; write k(i+1) from s0; load k(i+3)
        mm(1);
        if (2 * t + 2 < 16) wr(s0, 0);
        if (2 * t + 4 < 16) ld(s0, (2 * t + 4) * 64);
        asm volatile("s_waitcnt lgkmcnt(0)" ::: "memory");
        __builtin_amdgcn_s_barrier();
    }
}

// ---------------- persistent fused LSTM kernel ------------------------------
// 256 blocks, 1/CU, 512 threads. xcd owns gate-col slice [512x,512x+512);
// slot -> mt (0..7) x nb (0..3). Round r: L0(r) [r<128] + L1(r-1) [r>0];
// one flag inc per round; cnt[mt] target 32*r.

__global__ __launch_bounds__(512)
void lstm_persist(const float* __restrict__ x,
                  const __bf16* __restrict__ W0p, const __bf16* __restrict__ W1p,
                  const __bf16* __restrict__ Wfcp,
                  const float* __restrict__ Wi0p, const float* __restrict__ b1p,
                  const float* __restrict__ bfc,
                  __bf16* __restrict__ bufA, __bf16* __restrict__ bufB,
                  char* __restrict__ flagpage, float* __restrict__ out) {
    __shared__ __attribute__((aligned(16))) char Alds[2 * 8192];      // 16 KB
    __shared__ __attribute__((aligned(16))) char B0lds[2 * 16384];    // 32 KB
    __shared__ __attribute__((aligned(16))) char B1lds[2 * 16384];    // 32 KB
    __shared__ float Aux1[128];
    __shared__ float Xlds[64 * 9];
    __shared__ float Wxlds[128 * 9];
    __shared__ int role[2];

    const int tid = threadIdx.x;

    // ---- claim XCD-local role ----
    if (tid == 0) {
        int xcd = __builtin_amdgcn_s_getreg(63508) & 7;   // HW_REG_XCC_ID
        int* xcnt = (int*)(flagpage + 1024) + xcd;
        int slot = __hip_atomic_fetch_add(xcnt, 1, __ATOMIC_RELAXED,
                                          __HIP_MEMORY_SCOPE_AGENT);
        role[0] = xcd; role[1] = slot;
    }
    __syncthreads();
    const int xcd = role[0];
    const int sl  = role[1];          // 0..31
    const int mt = sl >> 2, nb = sl & 3;
    const int m0 = mt * 64;
    const int n0 = xcd * 512 + nb * 128;
    int* cnt = (int*)(flagpage + (size_t)mt * 64);

    // one-time epilogue constants
    if (tid < 128) {
        Aux1[tid] = b1p[n0 + tid];
    } else if (tid < 256) {
        int nl = tid - 128;
        const float* sp = Wi0p + (n0 + nl) * 8;
        float* d = Wxlds + nl * 9;
        #pragma unroll
        for (int q = 0; q < 8; ++q) d[q] = sp[q];
    }

    const int b_r = tid >> 2;
    const int b_c = (tid & 3) << 4;
    const int l  = tid & 63, w = tid >> 6;
    const int wm = w & 3,   wn = w >> 2;
    const int lj = l & 15,  lq = l >> 4;
    const int jc = (n0 >> 2) + wn * 16 + lj;   // h column in [0,1024)

    const __bf16* w0row = W0p + (size_t)(n0 + b_r) * 1024 + b_c;
    const __bf16* w1row = W1p + (size_t)(n0 + b_r) * 2048 + b_c;

    float c0[4], c1[4];
    #pragma unroll
    for (int r = 0; r < 4; ++r) { c0[r] = 0.f; c1[r] = 0.f; }

    f32x4 acc0[4], acc1[4];

    for (int r = 0; r <= 128; ++r) {
        const bool do0 = (r < 128), do1 = (r > 0);
        const __bf16* haPrev = bufA + (size_t)(r % 3) * HSZ;        // h_a(r-1)
        __bf16*       haOut  = bufA + (size_t)((r + 1) % 3) * HSZ;  // h_a(r)
        const __bf16* hbPrev = bufB + (size_t)((r + 2) % 3) * HSZ;  // h_b(r-2)
        __bf16*       hbOut  = bufB + (size_t)(r % 3) * HSZ;        // h_b(r-1)

        if (tid == 0) spin_ge(cnt, 32 * r);
        __syncthreads();
        inv_l1();

        // stage x_r (read-only input)
        if (do0 && tid < 64) {
            const float* xr = x + (m0 + tid) * 896 + r * 7;
            float* d = Xlds + tid * 9;
            #pragma unroll
            for (int q = 0; q < 7; ++q) d[q] = xr[q];
            d[7] = 1.0f;
        }

        #pragma unroll
        for (int j = 0; j < 4; ++j) {
            acc0[j] = (f32x4){0.f, 0.f, 0.f, 0.f};
            acc1[j] = (f32x4){0.f, 0.f, 0.f, 0.f};
        }

        const __bf16* abase = haPrev + m0 * 1024;
        if (do0 && do1)
            floop<true, true >(abase, w0row, w1row, tid, Alds, B0lds, B1lds, acc0, acc1);
        else if (do0)
            floop<true, false>(abase, w0row, w1row, tid, Alds, B0lds, B1lds, acc0, acc1);
        else
            floop<false, true>(abase, w0row, w1row, tid, Alds, B0lds, B1lds, acc0, acc1);

        if (do1) {   // h_b(r-2) half of layer-1 GEMM (k in [1024,2048))
            floop<false, true>(hbPrev + m0 * 1024, w0row, w1row + 1024,
                               tid, Alds, B0lds, B1lds, acc0, acc1);
        }

        if (do0) {   // L0 epilogue: cell update + EA store h_a(r)
            #pragma unroll
            for (int rr = 0; rr < 4; ++rr) {
                int ml = wm * 16 + lq * 4 + rr;
                int m  = m0 + ml;
                float pre[4];
                #pragma unroll
                for (int g = 0; g < 4; ++g) pre[g] = acc0[g][rr];
                const float* xr = Xlds + ml * 9;
                #pragma unroll
                for (int g = 0; g < 4; ++g) {
                    const float* wx = Wxlds + (wn * 64 + g * 16 + lj) * 9;
                    float sv = 0.f;
                    #pragma unroll
                    for (int q = 0; q < 8; ++q) sv += xr[q] * wx[q];
                    pre[g] += sv;
                }
                float ig = sigm_f(pre[0]);
                float fg = sigm_f(pre[1]);
                float gv = tanh_f(pre[2]);
                float og = sigm_f(pre[3]);
                float cn = fg * c0[rr] + ig * gv;
                c0[rr] = cn;
                float hv = og * tanh_f(cn);
                unsigned u32 = __builtin_bit_cast(unsigned, hv);
                unsigned hu = (u32 + 0x7fffu + ((u32 >> 16) & 1u)) >> 16;
                int pv = __shfl_xor((int)hu, 1, 64);
                if ((lj & 1) == 0)
                    store_ea((unsigned*)(haOut + (size_t)m * 1024 + jc),
                             hu | ((unsigned)pv << 16));
            }
        }
        if (do1) {   // L1 epilogue: cell update + EA store h_b(r-1)
            #pragma unroll
            for (int rr = 0; rr < 4; ++rr) {
                int m = m0 + wm * 16 + lq * 4 + rr;
                float pre[4];
                #pragma unroll
                for (int g = 0; g < 4; ++g)
                    pre[g] = acc1[g][rr] + Aux1[wn * 64 + g * 16 + lj];
                float ig = sigm_f(pre[0]);
                float fg = sigm_f(pre[1]);
                float gv = tanh_f(pre[2]);
                float og = sigm_f(pre[3]);
                float cn = fg * c1[rr] + ig * gv;
                c1[rr] = cn;
                float hv = og * tanh_f(cn);
                unsigned u32 = __builtin_bit_cast(unsigned, hv);
                unsigned hu = (u32 + 0x7fffu + ((u32 >> 16) & 1u)) >> 16;
                int pv = __shfl_xor((int)hu, 1, 64);
                if ((lj & 1) == 0)
                    store_ea((unsigned*)(hbOut + (size_t)m * 1024 + jc),
                             hu | ((unsigned)pv << 16));
            }
        }
        __syncthreads();                 // vmcnt(0): EA stores performed
        if (tid == 0) signal_inc(cnt);
    }

    // ---- final FC: pred = h_b(127) @ Wfc^T + bfc  (nb==0, xcd<6) -----------
    if (nb == 0 && xcd < 6) {
        const int n0fc = xcd * 128;
        if (tid == 0) spin_ge(cnt, 32 * 129);
        __syncthreads();
        inv_l1();
        if (tid < 128) {
            int n = n0fc + tid;
            Aux1[tid] = (n < 672) ? bfc[n] : 0.f;
        }
        #pragma unroll
        for (int j = 0; j < 4; ++j)
            acc0[j] = (f32x4){0.f, 0.f, 0.f, 0.f};
        // h_b(127) written in round 128 into bufB slot 128%3 = 2
        floop<true, false>(bufB + (size_t)2 * HSZ + m0 * 1024,
                           Wfcp + (size_t)(n0fc + b_r) * 1024 + b_c, nullptr,
                           tid, Alds, B0lds, B1lds, acc0, acc1);
        #pragma unroll
        for (int rr = 0; rr < 4; ++rr) {
            int m = m0 + wm * 16 + lq * 4 + rr;
            #pragma unroll
            for (int ni = 0; ni < 4; ++ni) {
                int n = n0fc + wn * 64 + ni * 16 + lj;
                if (n < 672)
                    out[m * 672 + n] = acc0[ni][rr] + Aux1[wn * 64 + ni * 16 + lj];
            }
        }
    }
}

// ---------------- workspace layout (bytes) ----------------------------------
#define O_W0P   0u            // 4096*1024*2  = 8388608
#define O_W1P   8388608u      // 4096*2048*2  = 16777216
#define O_WFCP  25165824u     // 768*1024*2   = 1572864
#define O_WI0P  26738688u     // 4096*8*4     = 131072
#define O_B1P   26869760u     // 4096*4       = 16384
#define O_FLG   26886144u     // 2048: cnt[8]@mt*64, xcnt@1024
#define O_BA    26888192u     // bufA[3] = 3*1048576  (slot0 zeroed = h_a(-1))
#define O_BB    30033920u     // bufB[3] = 3*1048576  (slot0 zeroed = h_b(-1))
#define WS_NEED 33179648u

extern "C" void kernel_launch(void* const* d_in, const int* in_sizes, int n_in,
                              void* d_out, int out_size, void* d_ws, size_t ws_size,
                              hipStream_t stream) {
    const float* x   = (const float*)d_in[0];
    const float* Wi0 = (const float*)d_in[1];
    const float* Wh0 = (const float*)d_in[2];
    const float* b0  = (const float*)d_in[3];
    const float* Wi1 = (const float*)d_in[4];
    const float* Wh1 = (const float*)d_in[5];
    const float* b1  = (const float*)d_in[6];
    const float* Wfc = (const float*)d_in[7];
    const float* bfc = (const float*)d_in[8];
    float* out = (float*)d_out;
    char*  ws  = (char*)d_ws;
    if (ws_size < WS_NEED) return;

    __bf16* W0p  = (__bf16*)(ws + O_W0P);
    __bf16* W1p  = (__bf16*)(ws + O_W1P);
    __bf16* Wfcp = (__bf16*)(ws + O_WFCP);
    float*  Wi0p = (float*)(ws + O_WI0P);
    float*  b1p  = (float*)(ws + O_B1P);
    char*   flg  = (char*)(ws + O_FLG);
    __bf16* bufA = (__bf16*)(ws + O_BA);
    __bf16* bufB = (__bf16*)(ws + O_BB);

    // zero flags + bufA slot0 (contiguous), and bufB slot0
    hipMemsetAsync(ws + O_FLG, 0, 2048u + 1048576u, stream);
    hipMemsetAsync(ws + O_BB, 0, 1048576u, stream);

    prep_w0   <<<4096, 256, 0, stream>>>(Wh0, W0p);
    prep_w1   <<<8192, 256, 0, stream>>>(Wi1, Wh1, W1p);
    prep_wfc  <<<768,  256, 0, stream>>>(Wfc, Wfcp);
    prep_small<<<16,   256, 0, stream>>>(Wi0, b0, b1, Wi0p, b1p);

    lstm_persist<<<256, 512, 0, stream>>>(x, W0p, W1p, Wfcp, Wi0p, b1p, bfc,
                                          bufA, bufB, flg, out);
}

// Round 6
// 2955.849 us; speedup vs baseline: 2.3736x; 2.3736x over previous
//
#include <hip/hip_runtime.h>
#include <hip/hip_bf16.h>

// ---------------------------------------------------------------------------
// LSTM_66675072303478: 2-layer LSTM (B=512,S=128,E=7,H=1024) + FC(1024->672)
//
// v17 = v15 skeleton (global pattern byte-identical, weights L2-resident)
// with two fixes derived from the v15/v16 ledger:
//  (1) Wave retile 4(m)x2(n) -> 2(m)x4(n), wave tile 32m x 32n per layer:
//      LDS reads drop 18->12 per dual iter (144->96 KB/CU/iter, the v15
//      binder). New gate perm np=(j>>3)*32+g*8+(j&7): all 4 gates of a
//      hidden unit inside one wave's 32-col slice; combined with ONE
//      shfl_xor(8) + selects. h stores via LDS staging + cooperative
//      64B-per-row EA stores (v14-proven, no write amplification).
//  (2) v16's counted-vmcnt raw-barrier pipeline, reimplemented FLAT:
//      named uint4 locals + macros -- NO structs, NO lambdas, so the asm
//      "memory" clobber cannot force allocas to LDS/scratch (v16 pathology:
//      LDS +40KB = 512x80B BRegs, WRITE 5.9GB scratch). lgkmcnt(0)-only
//      barriers keep global loads in flight (issue->use = 2 iters).
//      sched_barrier(0) after each s_barrier per rule #18.
//  - proven & kept: EA h stores + 3-slot rotation + L1-only inv, one
//    flag/round, XOR swizzle phys=row*128+((chunk^(row&7))<<4) (0 conflicts).
// ---------------------------------------------------------------------------

typedef __bf16 bf16x8 __attribute__((ext_vector_type(8)));
typedef float  f32x4  __attribute__((ext_vector_type(4)));

#define HSZ   (512 * 1024)  // one h buffer: 512 rows x 1024 cols (bf16)

__device__ __forceinline__ float tanh_f(float x) {
    x = fminf(30.f, fmaxf(-30.f, x));
    float e = __expf(-2.0f * x);
    return (1.0f - e) / (1.0f + e);
}

// np = (j>>3)*32 + g*8 + (j&7)  ->  original gate-major row g*1024 + j
__device__ __forceinline__ int perm_row(int np) {
    int g = (np >> 3) & 3;
    int j = ((np >> 5) << 3) | (np & 7);
    return g * 1024 + j;
}

// ---- relaxed-only flag ops (NO acquire/release -> no L2 inv/wb) ------------
__device__ __forceinline__ void spin_ge(const int* p, int target) {
    while (__hip_atomic_load(p, __ATOMIC_RELAXED, __HIP_MEMORY_SCOPE_AGENT) < target)
        __builtin_amdgcn_s_sleep(1);
}
__device__ __forceinline__ void signal_inc(int* p) {
    __hip_atomic_fetch_add(p, 1, __ATOMIC_RELAXED, __HIP_MEMORY_SCOPE_AGENT);
}
// L1-only invalidate (CU scope). Leaves L2/MALL intact; compiler fence.
__device__ __forceinline__ void inv_l1() {
    asm volatile("buffer_inv" ::: "memory");
}
// EA-point coherent dword store: bypasses L2s -> visible chip-wide.
__device__ __forceinline__ void store_ea(unsigned* p, unsigned v) {
    __hip_atomic_store(p, v, __ATOMIC_RELAXED, __HIP_MEMORY_SCOPE_AGENT);
}

// ---------------- weight prep kernels (run every call) ----------------------

__global__ void prep_w0(const float* __restrict__ Wh0, __bf16* __restrict__ W0p) {
    int idx = blockIdx.x * 256 + threadIdx.x;
    int np = idx >> 8, k4 = (idx & 255) << 2;
    int r = perm_row(np);
    float4 v = *(const float4*)(Wh0 + r * 1024 + k4);
    __bf16* o = W0p + np * 1024 + k4;
    o[0] = (__bf16)v.x; o[1] = (__bf16)v.y; o[2] = (__bf16)v.z; o[3] = (__bf16)v.w;
}

__global__ void prep_w1(const float* __restrict__ Wi1, const float* __restrict__ Wh1,
                        __bf16* __restrict__ W1p) {
    int idx = blockIdx.x * 256 + threadIdx.x;
    int np = idx >> 9, k4 = (idx & 511) << 2;
    int r = perm_row(np);
    const float* s = (k4 < 1024) ? (Wi1 + r * 1024 + k4) : (Wh1 + r * 1024 + (k4 - 1024));
    float4 v = *(const float4*)s;
    __bf16* o = W1p + np * 2048 + k4;
    o[0] = (__bf16)v.x; o[1] = (__bf16)v.y; o[2] = (__bf16)v.z; o[3] = (__bf16)v.w;
}

__global__ void prep_wfc(const float* __restrict__ Wfc, __bf16* __restrict__ Wfcp) {
    int idx = blockIdx.x * 256 + threadIdx.x;
    int n = idx >> 8, k4 = (idx & 255) << 2;
    __bf16* o = Wfcp + n * 1024 + k4;
    if (n < 672) {
        float4 v = *(const float4*)(Wfc + n * 1024 + k4);
        o[0] = (__bf16)v.x; o[1] = (__bf16)v.y; o[2] = (__bf16)v.z; o[3] = (__bf16)v.w;
    } else {
        o[0] = (__bf16)0.f; o[1] = (__bf16)0.f; o[2] = (__bf16)0.f; o[3] = (__bf16)0.f;
    }
}

__global__ void prep_small(const float* __restrict__ Wi0, const float* __restrict__ b0,
                           const float* __restrict__ b1,
                           float* __restrict__ Wi0p, float* __restrict__ b1p) {
    int np = blockIdx.x * 256 + threadIdx.x;
    int r = perm_row(np);
    float* o = Wi0p + np * 8;
    #pragma unroll
    for (int q = 0; q < 7; ++q) o[q] = Wi0[r * 7 + q];
    o[7] = b0[r];
    b1p[np] = b1[r];
}

// ---------------- fused pipelined K=1024 sub-loop (512 threads) -------------
// Tile 64x128, 8 waves in 2(m)x4(n), wave tile 32m x 32n per layer, BK=64,
// LDS dbuf. Per dual iter: 12 ds_read_b128 + 16 MFMA per wave.
// Two flat register load-sets; sync = lgkmcnt(0) + raw s_barrier (+sched
// fence); global loads stay in flight (counted vmcnt at the ds_write).
// LDS layout: 128B rows, phys = row*128 + ((chunk ^ (row&7))<<4).

template <bool D0, bool D1>
__device__ __forceinline__ void floop(const __bf16* __restrict__ abase,
                                      const __bf16* __restrict__ w0row,
                                      const __bf16* __restrict__ w1row,
                                      int tid,
                                      char* AldsB, char* B0ldsB, char* B1ldsB,
                                      f32x4 (&acc0)[2][2], f32x4 (&acc1)[2][2]) {
    const int a_r = tid >> 3;             // 0..63
    const int a_c = (tid & 7) << 3;       // 0..56 step 8 (16 B)
    const int b_r = tid >> 2;             // 0..127
    const int l  = tid & 63, w = tid >> 6;
    const int wm2 = w >> 2, wn4 = w & 3;
    const int lj = l & 15,  lq = l >> 4;
    const int r7 = lj & 7;

    const __bf16* arw = abase + a_r * 1024 + a_c;

    const int awr  = a_r * 128 + (((tid & 7) ^ (a_r & 7)) << 4);
    const int bwr0 = b_r * 128 + (((((tid & 3) << 1) | 0) ^ (b_r & 7)) << 4);
    const int bwr1 = b_r * 128 + (((((tid & 3) << 1) | 1) ^ (b_r & 7)) << 4);
    const int rc0 = ((lq    ) ^ r7) << 4;
    const int rc1 = ((lq | 4) ^ r7) << 4;

    const char* ArowA  = AldsB  + (wm2 * 32      + lj) * 128;
    const char* ArowB  = AldsB  + (wm2 * 32 + 16 + lj) * 128;
    const char* B0rowA = B0ldsB + (wn4 * 32      + lj) * 128;
    const char* B0rowB = B0ldsB + (wn4 * 32 + 16 + lj) * 128;
    const char* B1rowA = B1ldsB + (wn4 * 32      + lj) * 128;
    const char* B1rowB = B1ldsB + (wn4 * 32 + 16 + lj) * 128;

    // flat register sets -- NO structs, NO lambdas (v16 alloca pathology)
    uint4 vA0, vP0, vP1, vQ0, vQ1;   // set 0
    uint4 vA1, vR0, vR1, vS0, vS1;   // set 1

#define FL_LD(Av, P0v, P1v, Q0v, Q1v, k0) do {                                 \
    Av = *(const uint4*)(arw + (k0));                                          \
    if (D0) { P0v = *(const uint4*)(w0row + (k0));                             \
              P1v = *(const uint4*)(w0row + (k0) + 8); }                       \
    if (D1) { Q0v = *(const uint4*)(w1row + (k0));                             \
              Q1v = *(const uint4*)(w1row + (k0) + 8); } } while (0)

#define FL_WR(Av, P0v, P1v, Q0v, Q1v, buf) do {                                \
    *(uint4*)(AldsB + (buf) * 8192 + awr) = Av;                                \
    if (D0) { *(uint4*)(B0ldsB + (buf) * 16384 + bwr0) = P0v;                  \
              *(uint4*)(B0ldsB + (buf) * 16384 + bwr1) = P1v; }                \
    if (D1) { *(uint4*)(B1ldsB + (buf) * 16384 + bwr0) = Q0v;                  \
              *(uint4*)(B1ldsB + (buf) * 16384 + bwr1) = Q1v; } } while (0)

#define FL_MM(bo) do {                                                         \
    _Pragma("unroll")                                                          \
    for (int s = 0; s < 2; ++s) {                                              \
        const int rc = s ? rc1 : rc0;                                          \
        bf16x8 af0 = *(const bf16x8*)(ArowA + (bo) * 8192 + rc);               \
        bf16x8 af1 = *(const bf16x8*)(ArowB + (bo) * 8192 + rc);               \
        if (D0) {                                                              \
            bf16x8 b00 = *(const bf16x8*)(B0rowA + (bo) * 16384 + rc);         \
            bf16x8 b01 = *(const bf16x8*)(B0rowB + (bo) * 16384 + rc);         \
            acc0[0][0] = __builtin_amdgcn_mfma_f32_16x16x32_bf16(af0, b00, acc0[0][0], 0, 0, 0); \
            acc0[1][0] = __builtin_amdgcn_mfma_f32_16x16x32_bf16(af1, b00, acc0[1][0], 0, 0, 0); \
            acc0[0][1] = __builtin_amdgcn_mfma_f32_16x16x32_bf16(af0, b01, acc0[0][1], 0, 0, 0); \
            acc0[1][1] = __builtin_amdgcn_mfma_f32_16x16x32_bf16(af1, b01, acc0[1][1], 0, 0, 0); \
        }                                                                      \
        if (D1) {                                                              \
            bf16x8 b10 = *(const bf16x8*)(B1rowA + (bo) * 16384 + rc);         \
            bf16x8 b11 = *(const bf16x8*)(B1rowB + (bo) * 16384 + rc);         \
            acc1[0][0] = __builtin_amdgcn_mfma_f32_16x16x32_bf16(af0, b10, acc1[0][0], 0, 0, 0); \
            acc1[1][0] = __builtin_amdgcn_mfma_f32_16x16x32_bf16(af1, b10, acc1[1][0], 0, 0, 0); \
            acc1[0][1] = __builtin_amdgcn_mfma_f32_16x16x32_bf16(af0, b11, acc1[0][1], 0, 0, 0); \
            acc1[1][1] = __builtin_amdgcn_mfma_f32_16x16x32_bf16(af1, b11, acc1[1][1], 0, 0, 0); \
        }                                                                      \
    } } while (0)

#define FL_SYNC() do {                                                         \
    asm volatile("s_waitcnt lgkmcnt(0)" ::: "memory");                         \
    __builtin_amdgcn_s_barrier();                                              \
    __builtin_amdgcn_sched_barrier(0); } while (0)

    // prologue: k0 -> buf0 (single vmcnt-full wait here); k1 -> s1; k2 -> s0
    FL_LD(vA0, vP0, vP1, vQ0, vQ1, 0);
    FL_WR(vA0, vP0, vP1, vQ0, vQ1, 0);
    FL_LD(vA1, vR0, vR1, vS0, vS1, 64);
    FL_LD(vA0, vP0, vP1, vQ0, vQ1, 128);
    FL_SYNC();

    for (int t = 0; t < 8; ++t) {
        // even iter 2t: consume buf0; write k(2t+1) from set1; load k(2t+3)
        FL_MM(0);
        FL_WR(vA1, vR0, vR1, vS0, vS1, 1);
        if (2 * t + 3 < 16) FL_LD(vA1, vR0, vR1, vS0, vS1, (2 * t + 3) * 64);
        FL_SYNC();
        // odd iter 2t+1: consume buf1; write k(2t+2) from set0; load k(2t+4)
        FL_MM(1);
        if (2 * t + 2 < 16) FL_WR(vA0, vP0, vP1, vQ0, vQ1, 0);
        if (2 * t + 4 < 16) FL_LD(vA0, vP0, vP1, vQ0, vQ1, (2 * t + 4) * 64);
        FL_SYNC();
    }
#undef FL_LD
#undef FL_WR
#undef FL_MM
#undef FL_SYNC
}

// ---------------- persistent fused LSTM kernel ------------------------------
// 256 blocks, 1/CU, 512 threads. xcd owns gate-col slice [512x,512x+512);
// slot -> mt (0..7) x nb (0..3). Round r: L0(r) [r<128] + L1(r-1) [r>0];
// one flag inc per round; cnt[mt] target 32*r.

__global__ __launch_bounds__(512)
void lstm_persist(const float* __restrict__ x,
                  const __bf16* __restrict__ W0p, const __bf16* __restrict__ W1p,
                  const __bf16* __restrict__ Wfcp,
                  const float* __restrict__ Wi0p, const float* __restrict__ b1p,
                  const float* __restrict__ bfc,
                  __bf16* __restrict__ bufA, __bf16* __restrict__ bufB,
                  char* __restrict__ flagpage, float* __restrict__ out) {
    __shared__ __attribute__((aligned(16))) char Alds[2 * 8192];      // 16 KB
    __shared__ __attribute__((aligned(16))) char B0lds[2 * 16384];    // 32 KB
    __shared__ __attribute__((aligned(16))) char B1lds[2 * 16384];    // 32 KB
    __shared__ unsigned Hs[2][64 * 16];                               // 8 KB
    __shared__ float Aux1[128];
    __shared__ float Xlds[64 * 9];
    __shared__ float Wxlds[128 * 9];
    __shared__ int role[2];

    const int tid = threadIdx.x;

    // ---- claim XCD-local role ----
    if (tid == 0) {
        int xcd = __builtin_amdgcn_s_getreg(63508) & 7;   // HW_REG_XCC_ID
        int* xcnt = (int*)(flagpage + 1024) + xcd;
        int slot = __hip_atomic_fetch_add(xcnt, 1, __ATOMIC_RELAXED,
                                          __HIP_MEMORY_SCOPE_AGENT);
        role[0] = xcd; role[1] = slot;
    }
    __syncthreads();
    const int xcd = role[0];
    const int sl  = role[1];          // 0..31
    const int mt = sl >> 2, nb = sl & 3;
    const int m0 = mt * 64;
    const int n0 = xcd * 512 + nb * 128;
    int* cnt = (int*)(flagpage + (size_t)mt * 64);

    // one-time epilogue constants
    if (tid < 128) {
        Aux1[tid] = b1p[n0 + tid];
    } else if (tid < 256) {
        int nl = tid - 128;
        const float* sp = Wi0p + (n0 + nl) * 8;
        float* d = Wxlds + nl * 9;
        #pragma unroll
        for (int q = 0; q < 8; ++q) d[q] = sp[q];
    }
    __syncthreads();

    const int b_r = tid >> 2;
    const int b_c = (tid & 3) << 4;
    const int l  = tid & 63, w = tid >> 6;
    const int wm2 = w >> 2, wn4 = w & 3;
    const int lj = l & 15,  lq = l >> 4;
    const int lh = lj >> 3;                    // 0/1: gate half
    const int cg0 = wn4 * 32 + lj;             // gate-col (ni=0)
    const int cg1 = wn4 * 32 + 16 + lj;        // gate-col (ni=1)
    const float g2_1 = (lh == 0) ? 1.f : 0.f;  // ni=1,lj<8 -> tanh (gate 2)
    const float sc1 = 1.f + g2_1;

    // hoisted per-lane constants
    const float b1v0 = Aux1[cg0];
    const float b1v1 = Aux1[cg1];
    float wx0r[8], wx1r[8];
    #pragma unroll
    for (int q = 0; q < 8; ++q) {
        wx0r[q] = Wxlds[cg0 * 9 + q];
        wx1r[q] = Wxlds[cg1 * 9 + q];
    }

    const __bf16* w0row = W0p + (size_t)(n0 + b_r) * 1024 + b_c;
    const __bf16* w1row = W1p + (size_t)(n0 + b_r) * 2048 + b_c;

    float c0s[2][4], c1s[2][4];
    #pragma unroll
    for (int i = 0; i < 2; ++i)
        #pragma unroll
        for (int j = 0; j < 4; ++j) { c0s[i][j] = 0.f; c1s[i][j] = 0.f; }

    f32x4 acc0[2][2], acc1[2][2];

    for (int r = 0; r <= 128; ++r) {
        const bool do0 = (r < 128), do1 = (r > 0);
        const __bf16* haPrev = bufA + (size_t)(r % 3) * HSZ;        // h_a(r-1)
        __bf16*       haOut  = bufA + (size_t)((r + 1) % 3) * HSZ;  // h_a(r)
        const __bf16* hbPrev = bufB + (size_t)((r + 2) % 3) * HSZ;  // h_b(r-2)
        __bf16*       hbOut  = bufB + (size_t)(r % 3) * HSZ;        // h_b(r-1)

        if (tid == 0) spin_ge(cnt, 32 * r);
        __syncthreads();
        inv_l1();

        // stage x_r (read-only input)
        if (do0 && tid < 64) {
            const float* xr = x + (m0 + tid) * 896 + r * 7;
            float* d = Xlds + tid * 9;
            #pragma unroll
            for (int q = 0; q < 7; ++q) d[q] = xr[q];
            d[7] = 1.0f;
        }

        #pragma unroll
        for (int i = 0; i < 2; ++i)
            #pragma unroll
            for (int j = 0; j < 2; ++j) {
                acc0[i][j] = (f32x4){0.f, 0.f, 0.f, 0.f};
                acc1[i][j] = (f32x4){0.f, 0.f, 0.f, 0.f};
            }

        const __bf16* abase = haPrev + m0 * 1024;
        if (do0 && do1)
            floop<true, true >(abase, w0row, w1row, tid, Alds, B0lds, B1lds, acc0, acc1);
        else if (do0)
            floop<true, false>(abase, w0row, w1row, tid, Alds, B0lds, B1lds, acc0, acc1);
        else
            floop<false, true>(abase, w0row, w1row, tid, Alds, B0lds, B1lds, acc0, acc1);

        if (do1) {   // h_b(r-2) half of layer-1 GEMM (k in [1024,2048))
            floop<false, true>(hbPrev + m0 * 1024, w0row, w1row + 1024,
                               tid, Alds, B0lds, B1lds, acc0, acc1);
        }

        if (do0) {   // L0 epilogue: gates -> shfl(8) combine -> stage in Hs
            #pragma unroll
            for (int mi = 0; mi < 2; ++mi) {
                #pragma unroll
                for (int rr = 0; rr < 4; ++rr) {
                    int row = wm2 * 32 + mi * 16 + lq * 4 + rr;
                    const float* xr = Xlds + row * 9;
                    float pre0 = acc0[mi][0][rr];
                    float pre1 = acc0[mi][1][rr];
                    #pragma unroll
                    for (int q = 0; q < 8; ++q) {
                        pre0 += xr[q] * wx0r[q];
                        pre1 += xr[q] * wx1r[q];
                    }
                    float px0 = fminf(30.f, fmaxf(-30.f, pre0));
                    float e0  = __expf(-px0);
                    float a0  = 1.f / (1.f + e0);                    // i or f
                    float px1 = fminf(30.f, fmaxf(-30.f, pre1 * sc1));
                    float e1  = __expf(-px1);
                    float a1  = (1.f - g2_1 * e1) / (1.f + e1);      // g or o
                    float p0 = __shfl_xor(a0, 8, 64);
                    float p1 = __shfl_xor(a1, 8, 64);
                    float ig = lh ? p0 : a0;
                    float fg = lh ? a0 : p0;
                    float gv = lh ? p1 : a1;
                    float og = lh ? a1 : p1;
                    float cn = fg * c0s[mi][rr] + ig * gv;
                    c0s[mi][rr] = cn;
                    float hv = og * tanh_f(cn);
                    unsigned u32 = __builtin_bit_cast(unsigned, hv);
                    unsigned hu = (u32 + 0x7fffu + ((u32 >> 16) & 1u)) >> 16;
                    int pv = __shfl_xor((int)hu, 1, 64);
                    if (lh == 0 && (lj & 1) == 0)
                        Hs[0][row * 16 + wn4 * 4 + (lj >> 1)] = hu | ((unsigned)pv << 16);
                }
            }
        }
        if (do1) {   // L1 epilogue
            #pragma unroll
            for (int mi = 0; mi < 2; ++mi) {
                #pragma unroll
                for (int rr = 0; rr < 4; ++rr) {
                    int row = wm2 * 32 + mi * 16 + lq * 4 + rr;
                    float pre0 = acc1[mi][0][rr] + b1v0;
                    float pre1 = acc1[mi][1][rr] + b1v1;
                    float px0 = fminf(30.f, fmaxf(-30.f, pre0));
                    float e0  = __expf(-px0);
                    float a0  = 1.f / (1.f + e0);
                    float px1 = fminf(30.f, fmaxf(-30.f, pre1 * sc1));
                    float e1  = __expf(-px1);
                    float a1  = (1.f - g2_1 * e1) / (1.f + e1);
                    float p0 = __shfl_xor(a0, 8, 64);
                    float p1 = __shfl_xor(a1, 8, 64);
                    float ig = lh ? p0 : a0;
                    float fg = lh ? a0 : p0;
                    float gv = lh ? p1 : a1;
                    float og = lh ? a1 : p1;
                    float cn = fg * c1s[mi][rr] + ig * gv;
                    c1s[mi][rr] = cn;
                    float hv = og * tanh_f(cn);
                    unsigned u32 = __builtin_bit_cast(unsigned, hv);
                    unsigned hu = (u32 + 0x7fffu + ((u32 >> 16) & 1u)) >> 16;
                    int pv = __shfl_xor((int)hu, 1, 64);
                    if (lh == 0 && (lj & 1) == 0)
                        Hs[1][row * 16 + wn4 * 4 + (lj >> 1)] = hu | ((unsigned)pv << 16);
                }
            }
        }
        __syncthreads();                 // staging complete

        // cooperative wide EA stores: 4 rows x 64B contiguous per wave instr
        {
            #pragma unroll
            for (int pass = 0; pass < 2; ++pass) {
                int d = pass * 512 + tid;
                int row = d >> 4, col = d & 15;
                size_t off = (size_t)(m0 + row) * 512 + (n0 >> 3) + col;
                if (do0) store_ea((unsigned*)haOut + off, Hs[0][d]);
                if (do1) store_ea((unsigned*)hbOut + off, Hs[1][d]);
            }
        }
        __syncthreads();                 // vmcnt(0): EA stores performed
        if (tid == 0) signal_inc(cnt);
    }

    // ---- final FC: pred = h_b(127) @ Wfc^T + bfc  (nb==0, xcd<6) -----------
    if (nb == 0 && xcd < 6) {
        const int n0fc = xcd * 128;
        if (tid == 0) spin_ge(cnt, 32 * 129);
        __syncthreads();
        inv_l1();
        if (tid < 128) {
            int n = n0fc + tid;
            Aux1[tid] = (n < 672) ? bfc[n] : 0.f;
        }
        #pragma unroll
        for (int i = 0; i < 2; ++i)
            #pragma unroll
            for (int j = 0; j < 2; ++j)
                acc0[i][j] = (f32x4){0.f, 0.f, 0.f, 0.f};
        // h_b(127) written in round 128 into bufB slot 128%3 = 2
        floop<true, false>(bufB + (size_t)2 * HSZ + m0 * 1024,
                           Wfcp + (size_t)(n0fc + b_r) * 1024 + b_c, nullptr,
                           tid, Alds, B0lds, B1lds, acc0, acc1);
        const float bv0 = Aux1[cg0];
        const float bv1 = Aux1[cg1];
        #pragma unroll
        for (int mi = 0; mi < 2; ++mi) {
            #pragma unroll
            for (int rr = 0; rr < 4; ++rr) {
                int m = m0 + wm2 * 32 + mi * 16 + lq * 4 + rr;
                int nA = n0fc + cg0;
                int nB = n0fc + cg1;
                if (nA < 672) out[m * 672 + nA] = acc0[mi][0][rr] + bv0;
                if (nB < 672) out[m * 672 + nB] = acc0[mi][1][rr] + bv1;
            }
        }
    }
}

// ---------------- workspace layout (bytes) ----------------------------------
#define O_W0P   0u            // 4096*1024*2  = 8388608
#define O_W1P   8388608u      // 4096*2048*2  = 16777216
#define O_WFCP  25165824u     // 768*1024*2   = 1572864
#define O_WI0P  26738688u     // 4096*8*4     = 131072
#define O_B1P   26869760u     // 4096*4       = 16384
#define O_FLG   26886144u     // 2048: cnt[8]@mt*64, xcnt@1024
#define O_BA    26888192u     // bufA[3] = 3*1048576  (slot0 zeroed = h_a(-1))
#define O_BB    30033920u     // bufB[3] = 3*1048576  (slot0 zeroed = h_b(-1))
#define WS_NEED 33179648u

extern "C" void kernel_launch(void* const* d_in, const int* in_sizes, int n_in,
                              void* d_out, int out_size, void* d_ws, size_t ws_size,
                              hipStream_t stream) {
    const float* x   = (const float*)d_in[0];
    const float* Wi0 = (const float*)d_in[1];
    const float* Wh0 = (const float*)d_in[2];
    const float* b0  = (const float*)d_in[3];
    const float* Wi1 = (const float*)d_in[4];
    const float* Wh1 = (const float*)d_in[5];
    const float* b1  = (const float*)d_in[6];
    const float* Wfc = (const float*)d_in[7];
    const float* bfc = (const float*)d_in[8];
    float* out = (float*)d_out;
    char*  ws  = (char*)d_ws;
    if (ws_size < WS_NEED) return;

    __bf16* W0p  = (__bf16*)(ws + O_W0P);
    __bf16* W1p  = (__bf16*)(ws + O_W1P);
    __bf16* Wfcp = (__bf16*)(ws + O_WFCP);
    float*  Wi0p = (float*)(ws + O_WI0P);
    float*  b1p  = (float*)(ws + O_B1P);
    char*   flg  = (char*)(ws + O_FLG);
    __bf16* bufA = (__bf16*)(ws + O_BA);
    __bf16* bufB = (__bf16*)(ws + O_BB);

    // zero flags + bufA slot0 (contiguous), and bufB slot0
    hipMemsetAsync(ws + O_FLG, 0, 2048u + 1048576u, stream);
    hipMemsetAsync(ws + O_BB, 0, 1048576u, stream);

    prep_w0   <<<4096, 256, 0, stream>>>(Wh0, W0p);
    prep_w1   <<<8192, 256, 0, stream>>>(Wi1, Wh1, W1p);
    prep_wfc  <<<768,  256, 0, stream>>>(Wfc, Wfcp);
    prep_small<<<16,   256, 0, stream>>>(Wi0, b0, b1, Wi0p, b1p);

    lstm_persist<<<256, 512, 0, stream>>>(x, W0p, W1p, Wfcp, Wi0p, b1p, bfc,
                                          bufA, bufB, flg, out);
}

// Round 8
// 2827.842 us; speedup vs baseline: 2.4810x; 1.0453x over previous
//
#include <hip/hip_runtime.h>
#include <hip/hip_bf16.h>

// ---------------------------------------------------------------------------
// LSTM_66675072303478: 2-layer LSTM (B=512,S=128,E=7,H=1024) + FC(1024->672)
//
// v19 = v15 EXACTLY (best verified: 2924us; v11 skeleton + zero-conflict XOR
// LDS) with ONE protocol change: the per-round single flag is split into two
// phase flags (cntA for h_a, cntB for h_b).
//  - v18 post-mortem: 64x64 TLP restructure failed correctness un-nameably ->
//    reverted wholesale (rigor: don't patch unverifiable territory).
//  - v15/v17 ledger: LDS-traffic cut and vmcnt-drain removal both neutral ->
//    ~14us/round dead time is NOT intra-loop memory latency. Remaining
//    mechanism: once-per-round all-64-block rendezvous (max-of-64 skew +
//    flag propagation, serializing h_a and h_b dependencies at one point).
//  - Fix: Phase A = waitA(32r) -> floop1 (L0 + L1/Wi1-half on h_a(r-1)) ->
//    L0 epilogue + EA h_a(r) -> drain -> cntA++.   Phase B = waitB(32r)
//    [normally already satisfied -> ~0 stall] -> floop2 (Wh1-half on
//    h_b(r-2)) -> L1 epilogue + EA h_b(r-1) -> drain -> cntB++.
//    h_a(r) publishes ~60% into the round; stragglers delay others by their
//    phase-A remainder only; mid-round slack absorbs skew.
//  - Slot safety (3-slot, 32 writers): writer r phase A passed cntA>=32r =>
//    all blocks completed phase A of r-1 => completed round r-2 entirely =>
//    no live reader of bufA slot (r+1)%3. Symmetric for bufB via cntB.
//  - Everything else proven & untouched: 4(m)x2(n) waves, wave tile 16x64,
//    XOR swizzle phys=row*128+((chunk^(row&7))<<4) (0 conflicts), gate-
//    interleaved epilogue, EA h stores, L1-only inv, weights L2-resident.
// ---------------------------------------------------------------------------

typedef __bf16 bf16x8 __attribute__((ext_vector_type(8)));
typedef float  f32x4  __attribute__((ext_vector_type(4)));

#define HSZ   (512 * 1024)  // one h buffer: 512 rows x 1024 cols (bf16)

__device__ __forceinline__ float sigm_f(float x) {
    x = fminf(30.f, fmaxf(-30.f, x));
    return 1.0f / (1.0f + __expf(-x));
}
__device__ __forceinline__ float tanh_f(float x) {
    x = fminf(30.f, fmaxf(-30.f, x));
    float e = __expf(-2.0f * x);
    return (1.0f - e) / (1.0f + e);
}

// n' = (j/16)*64 + g*16 + (j%16)  ->  original gate-major row g*1024 + j
__device__ __forceinline__ int perm_row(int np) {
    int g = (np >> 4) & 3;
    int j = ((np >> 6) << 4) | (np & 15);
    return g * 1024 + j;
}

// ---- relaxed-only flag ops (NO acquire/release -> no L2 inv/wb) ------------
__device__ __forceinline__ void spin_ge(const int* p, int target) {
    while (__hip_atomic_load(p, __ATOMIC_RELAXED, __HIP_MEMORY_SCOPE_AGENT) < target)
        __builtin_amdgcn_s_sleep(1);
}
__device__ __forceinline__ void signal_inc(int* p) {
    __hip_atomic_fetch_add(p, 1, __ATOMIC_RELAXED, __HIP_MEMORY_SCOPE_AGENT);
}
// L1-only invalidate (CU scope). Leaves L2/MALL intact; compiler fence.
__device__ __forceinline__ void inv_l1() {
    asm volatile("buffer_inv" ::: "memory");
}
// EA-point coherent dword store: bypasses L2s -> visible chip-wide.
__device__ __forceinline__ void store_ea(unsigned* p, unsigned v) {
    __hip_atomic_store(p, v, __ATOMIC_RELAXED, __HIP_MEMORY_SCOPE_AGENT);
}

// ---------------- weight prep kernels (run every call) ----------------------

__global__ void prep_w0(const float* __restrict__ Wh0, __bf16* __restrict__ W0p) {
    int idx = blockIdx.x * 256 + threadIdx.x;
    int np = idx >> 8, k4 = (idx & 255) << 2;
    int r = perm_row(np);
    float4 v = *(const float4*)(Wh0 + r * 1024 + k4);
    __bf16* o = W0p + np * 1024 + k4;
    o[0] = (__bf16)v.x; o[1] = (__bf16)v.y; o[2] = (__bf16)v.z; o[3] = (__bf16)v.w;
}

__global__ void prep_w1(const float* __restrict__ Wi1, const float* __restrict__ Wh1,
                        __bf16* __restrict__ W1p) {
    int idx = blockIdx.x * 256 + threadIdx.x;
    int np = idx >> 9, k4 = (idx & 511) << 2;
    int r = perm_row(np);
    const float* s = (k4 < 1024) ? (Wi1 + r * 1024 + k4) : (Wh1 + r * 1024 + (k4 - 1024));
    float4 v = *(const float4*)s;
    __bf16* o = W1p + np * 2048 + k4;
    o[0] = (__bf16)v.x; o[1] = (__bf16)v.y; o[2] = (__bf16)v.z; o[3] = (__bf16)v.w;
}

__global__ void prep_wfc(const float* __restrict__ Wfc, __bf16* __restrict__ Wfcp) {
    int idx = blockIdx.x * 256 + threadIdx.x;
    int n = idx >> 8, k4 = (idx & 255) << 2;
    __bf16* o = Wfcp + n * 1024 + k4;
    if (n < 672) {
        float4 v = *(const float4*)(Wfc + n * 1024 + k4);
        o[0] = (__bf16)v.x; o[1] = (__bf16)v.y; o[2] = (__bf16)v.z; o[3] = (__bf16)v.w;
    } else {
        o[0] = (__bf16)0.f; o[1] = (__bf16)0.f; o[2] = (__bf16)0.f; o[3] = (__bf16)0.f;
    }
}

__global__ void prep_small(const float* __restrict__ Wi0, const float* __restrict__ b0,
                           const float* __restrict__ b1,
                           float* __restrict__ Wi0p, float* __restrict__ b1p) {
    int np = blockIdx.x * 256 + threadIdx.x;
    int r = perm_row(np);
    float* o = Wi0p + np * 8;
    #pragma unroll
    for (int q = 0; q < 7; ++q) o[q] = Wi0[r * 7 + q];
    o[7] = b0[r];
    b1p[np] = b1[r];
}

// ---------------- fused pipelined K=1024 sub-loop (512 threads) -------------
// Tile 64x128, 8 waves in 4(m)x2(n), wave tile 16x64, BK=64, LDS dbuf,
// 1 barrier/iter, global loads 2 iters ahead. D0 -> acc0 (W0), D1 -> acc1.
// LDS layout (A 64x64, B0/B1 128x64 per buf): 128B rows, 16B chunks stored at
//   phys = row*128 + ((chunk ^ (row&7))<<4)   -> conflict-free rd AND wr.

template <bool D0, bool D1>
__device__ __forceinline__ void floop(const __bf16* __restrict__ abase,
                                      const __bf16* __restrict__ w0row,
                                      const __bf16* __restrict__ w1row,
                                      int tid,
                                      char* AldsB, char* B0ldsB, char* B1ldsB,
                                      f32x4 (&acc0)[4], f32x4 (&acc1)[4]) {
    const int a_r = tid >> 3;             // 0..63
    const int a_c = (tid & 7) << 3;       // 0..56 step 8 (16 B)
    const int b_r = tid >> 2;             // 0..127
    const int b_c = (tid & 3) << 4;       // 0,16,32,48 (2 x 16 B each)
    const int l  = tid & 63, w = tid >> 6;
    const int wm = w & 3,   wn = w >> 2;
    const int lj = l & 15,  lq = l >> 4;
    const int r7 = lj & 7;

    const __bf16* arw = abase + a_r * 1024 + a_c;

    // swizzled LDS byte offsets (writes)
    const int awr  = a_r * 128 + (((tid & 7) ^ (a_r & 7)) << 4);
    const int bwr0 = b_r * 128 + (((((tid & 3) << 1) | 0) ^ (b_r & 7)) << 4);
    const int bwr1 = b_r * 128 + (((((tid & 3) << 1) | 1) ^ (b_r & 7)) << 4);
    // swizzled chunk offsets (reads), chunk = (s<<2)|lq
    const int rc0 = ((lq     ) ^ r7) << 4;   // s = 0
    const int rc1 = ((lq | 4 ) ^ r7) << 4;   // s = 1

    uint4 ra, rb00, rb01, rb10, rb11;
    auto ld = [&](int k0) {
        ra = *(const uint4*)(arw + k0);
        if (D0) {
            const __bf16* p = w0row + k0;
            rb00 = *(const uint4*)(p);
            rb01 = *(const uint4*)(p + 8);
        }
        if (D1) {
            const __bf16* p = w1row + k0;
            rb10 = *(const uint4*)(p);
            rb11 = *(const uint4*)(p + 8);
        }
    };
    auto wr = [&](int buf) {
        *(uint4*)(AldsB + buf * 8192 + awr) = ra;
        if (D0) {
            char* Bl = B0ldsB + buf * 16384;
            *(uint4*)(Bl + bwr0) = rb00;
            *(uint4*)(Bl + bwr1) = rb01;
        }
        if (D1) {
            char* Bl = B1ldsB + buf * 16384;
            *(uint4*)(Bl + bwr0) = rb10;
            *(uint4*)(Bl + bwr1) = rb11;
        }
    };

    ld(0);
    wr(0);
    ld(64);
    __syncthreads();

    const char* Ap  = AldsB  + (wm * 16 + lj) * 128;
    const char* B0p = B0ldsB + (wn * 64 + lj) * 128;
    const char* B1p = B1ldsB + (wn * 64 + lj) * 128;

    for (int it = 0; it < 16; ++it) {
        const int bo = it & 1;
        const char* Ab  = Ap  + bo * 8192;
        const char* B0b = B0p + bo * 16384;
        const char* B1b = B1p + bo * 16384;
        #pragma unroll
        for (int s = 0; s < 2; ++s) {
            const int rc = s ? rc1 : rc0;
            bf16x8 af = *(const bf16x8*)(Ab + rc);
            #pragma unroll
            for (int ni = 0; ni < 4; ++ni) {
                if (D0) {
                    bf16x8 b0 = *(const bf16x8*)(B0b + ni * 2048 + rc);
                    acc0[ni] = __builtin_amdgcn_mfma_f32_16x16x32_bf16(af, b0, acc0[ni], 0, 0, 0);
                }
                if (D1) {
                    bf16x8 b1 = *(const bf16x8*)(B1b + ni * 2048 + rc);
                    acc1[ni] = __builtin_amdgcn_mfma_f32_16x16x32_bf16(af, b1, acc1[ni], 0, 0, 0);
                }
            }
        }
        if (it + 1 < 16) wr((it + 1) & 1);       // data loaded 1 iter ago
        if (it + 2 < 16) ld((it + 2) * 64);      // 2-iter prefetch distance
        __syncthreads();
    }
}

// ---------------- persistent fused LSTM kernel ------------------------------
// 256 blocks, 1/CU, 512 threads. xcd owns gate-col slice [512x,512x+512);
// slot -> mt (0..7) x nb (0..3). Round r: phase A = L0(r) [r<128] + Wi1-half
// of L1(r-1); phase B = Wh1-half + L1 epilogue. cntA[mt] target 32r gates
// h_a(r-1); cntB[mt] target 32r gates h_b(r-2).

__global__ __launch_bounds__(512)
void lstm_persist(const float* __restrict__ x,
                  const __bf16* __restrict__ W0p, const __bf16* __restrict__ W1p,
                  const __bf16* __restrict__ Wfcp,
                  const float* __restrict__ Wi0p, const float* __restrict__ b1p,
                  const float* __restrict__ bfc,
                  __bf16* __restrict__ bufA, __bf16* __restrict__ bufB,
                  char* __restrict__ flagpage, float* __restrict__ out) {
    __shared__ __attribute__((aligned(16))) char Alds[2 * 8192];      // 16 KB
    __shared__ __attribute__((aligned(16))) char B0lds[2 * 16384];    // 32 KB
    __shared__ __attribute__((aligned(16))) char B1lds[2 * 16384];    // 32 KB
    __shared__ float Aux1[128];
    __shared__ float Xlds[64 * 9];
    __shared__ float Wxlds[128 * 9];
    __shared__ int role[2];

    const int tid = threadIdx.x;

    // ---- claim XCD-local role ----
    if (tid == 0) {
        int xcd = __builtin_amdgcn_s_getreg(63508) & 7;   // HW_REG_XCC_ID
        int* xcnt = (int*)(flagpage + 1024) + xcd;
        int slot = __hip_atomic_fetch_add(xcnt, 1, __ATOMIC_RELAXED,
                                          __HIP_MEMORY_SCOPE_AGENT);
        role[0] = xcd; role[1] = slot;
    }
    __syncthreads();
    const int xcd = role[0];
    const int sl  = role[1];          // 0..31
    const int mt = sl >> 2, nb = sl & 3;
    const int m0 = mt * 64;
    const int n0 = xcd * 512 + nb * 128;
    int* cntA = (int*)(flagpage + (size_t)mt * 64);          // offsets 0..448
    int* cntB = (int*)(flagpage + 512 + (size_t)mt * 64);    // offsets 512..960

    // one-time epilogue constants
    if (tid < 128) {
        Aux1[tid] = b1p[n0 + tid];
    } else if (tid < 256) {
        int nl = tid - 128;
        const float* sp = Wi0p + (n0 + nl) * 8;
        float* d = Wxlds + nl * 9;
        #pragma unroll
        for (int q = 0; q < 8; ++q) d[q] = sp[q];
    }

    const int b_r = tid >> 2;
    const int b_c = (tid & 3) << 4;
    const int l  = tid & 63, w = tid >> 6;
    const int wm = w & 3,   wn = w >> 2;
    const int lj = l & 15,  lq = l >> 4;
    const int jc = (n0 >> 2) + wn * 16 + lj;   // h column in [0,1024)

    const __bf16* w0row = W0p + (size_t)(n0 + b_r) * 1024 + b_c;
    const __bf16* w1row = W1p + (size_t)(n0 + b_r) * 2048 + b_c;

    float c0[4], c1[4];
    #pragma unroll
    for (int r = 0; r < 4; ++r) { c0[r] = 0.f; c1[r] = 0.f; }

    f32x4 acc0[4], acc1[4];

    for (int r = 0; r <= 128; ++r) {
        const bool do0 = (r < 128), do1 = (r > 0);
        const __bf16* haPrev = bufA + (size_t)(r % 3) * HSZ;        // h_a(r-1)
        __bf16*       haOut  = bufA + (size_t)((r + 1) % 3) * HSZ;  // h_a(r)
        const __bf16* hbPrev = bufB + (size_t)((r + 2) % 3) * HSZ;  // h_b(r-2)
        __bf16*       hbOut  = bufB + (size_t)(r % 3) * HSZ;        // h_b(r-1)

        // ================= phase A: needs h_a(r-1) =========================
        if (tid == 0) spin_ge(cntA, 32 * r);
        __syncthreads();
        inv_l1();

        // stage x_r (read-only input)
        if (do0 && tid < 64) {
            const float* xr = x + (m0 + tid) * 896 + r * 7;
            float* d = Xlds + tid * 9;
            #pragma unroll
            for (int q = 0; q < 7; ++q) d[q] = xr[q];
            d[7] = 1.0f;
        }

        #pragma unroll
        for (int j = 0; j < 4; ++j) {
            acc0[j] = (f32x4){0.f, 0.f, 0.f, 0.f};
            acc1[j] = (f32x4){0.f, 0.f, 0.f, 0.f};
        }

        const __bf16* abase = haPrev + m0 * 1024;
        if (do0 && do1)
            floop<true, true >(abase, w0row, w1row, tid, Alds, B0lds, B1lds, acc0, acc1);
        else if (do0)
            floop<true, false>(abase, w0row, w1row, tid, Alds, B0lds, B1lds, acc0, acc1);
        else
            floop<false, true>(abase, w0row, w1row, tid, Alds, B0lds, B1lds, acc0, acc1);

        if (do0) {   // L0 epilogue: cell update + EA store h_a(r)
            #pragma unroll
            for (int rr = 0; rr < 4; ++rr) {
                int ml = wm * 16 + lq * 4 + rr;
                int m  = m0 + ml;
                float pre[4];
                #pragma unroll
                for (int g = 0; g < 4; ++g) pre[g] = acc0[g][rr];
                const float* xr = Xlds + ml * 9;
                #pragma unroll
                for (int g = 0; g < 4; ++g) {
                    const float* wx = Wxlds + (wn * 64 + g * 16 + lj) * 9;
                    float sv = 0.f;
                    #pragma unroll
                    for (int q = 0; q < 8; ++q) sv += xr[q] * wx[q];
                    pre[g] += sv;
                }
                float ig = sigm_f(pre[0]);
                float fg = sigm_f(pre[1]);
                float gv = tanh_f(pre[2]);
                float og = sigm_f(pre[3]);
                float cn = fg * c0[rr] + ig * gv;
                c0[rr] = cn;
                float hv = og * tanh_f(cn);
                unsigned u32 = __builtin_bit_cast(unsigned, hv);
                unsigned hu = (u32 + 0x7fffu + ((u32 >> 16) & 1u)) >> 16;
                int pv = __shfl_xor((int)hu, 1, 64);
                if ((lj & 1) == 0)
                    store_ea((unsigned*)(haOut + (size_t)m * 1024 + jc),
                             hu | ((unsigned)pv << 16));
            }
        }
        __syncthreads();                 // vmcnt(0): h_a stores performed
        if (tid == 0) signal_inc(cntA);

        // ================= phase B: needs h_b(r-2) =========================
        if (tid == 0) spin_ge(cntB, 32 * r);
        __syncthreads();
        inv_l1();

        if (do1) {   // h_b(r-2) half of layer-1 GEMM (k in [1024,2048))
            floop<false, true>(hbPrev + m0 * 1024, w0row, w1row + 1024,
                               tid, Alds, B0lds, B1lds, acc0, acc1);

            // L1 epilogue: cell update + EA store h_b(r-1)
            #pragma unroll
            for (int rr = 0; rr < 4; ++rr) {
                int m = m0 + wm * 16 + lq * 4 + rr;
                float pre[4];
                #pragma unroll
                for (int g = 0; g < 4; ++g)
                    pre[g] = acc1[g][rr] + Aux1[wn * 64 + g * 16 + lj];
                float ig = sigm_f(pre[0]);
                float fg = sigm_f(pre[1]);
                float gv = tanh_f(pre[2]);
                float og = sigm_f(pre[3]);
                float cn = fg * c1[rr] + ig * gv;
                c1[rr] = cn;
                float hv = og * tanh_f(cn);
                unsigned u32 = __builtin_bit_cast(unsigned, hv);
                unsigned hu = (u32 + 0x7fffu + ((u32 >> 16) & 1u)) >> 16;
                int pv = __shfl_xor((int)hu, 1, 64);
                if ((lj & 1) == 0)
                    store_ea((unsigned*)(hbOut + (size_t)m * 1024 + jc),
                             hu | ((unsigned)pv << 16));
            }
        }
        __syncthreads();                 // vmcnt(0): h_b stores performed
        if (tid == 0) signal_inc(cntB);
    }

    // ---- final FC: pred = h_b(127) @ Wfc^T + bfc  (nb==0, xcd<6) -----------
    if (nb == 0 && xcd < 6) {
        const int n0fc = xcd * 128;
        if (tid == 0) spin_ge(cntB, 32 * 129);
        __syncthreads();
        inv_l1();
        if (tid < 128) {
            int n = n0fc + tid;
            Aux1[tid] = (n < 672) ? bfc[n] : 0.f;
        }
        #pragma unroll
        for (int j = 0; j < 4; ++j)
            acc0[j] = (f32x4){0.f, 0.f, 0.f, 0.f};
        // h_b(127) written in round 128 into bufB slot 128%3 = 2
        floop<true, false>(bufB + (size_t)2 * HSZ + m0 * 1024,
                           Wfcp + (size_t)(n0fc + b_r) * 1024 + b_c, nullptr,
                           tid, Alds, B0lds, B1lds, acc0, acc1);
        #pragma unroll
        for (int rr = 0; rr < 4; ++rr) {
            int m = m0 + wm * 16 + lq * 4 + rr;
            #pragma unroll
            for (int ni = 0; ni < 4; ++ni) {
                int n = n0fc + wn * 64 + ni * 16 + lj;
                if (n < 672)
                    out[m * 672 + n] = acc0[ni][rr] + Aux1[wn * 64 + ni * 16 + lj];
            }
        }
    }
}

// ---------------- workspace layout (bytes) ----------------------------------
#define O_W0P   0u            // 4096*1024*2  = 8388608
#define O_W1P   8388608u      // 4096*2048*2  = 16777216
#define O_WFCP  25165824u     // 768*1024*2   = 1572864
#define O_WI0P  26738688u     // 4096*8*4     = 131072
#define O_B1P   26869760u     // 4096*4       = 16384
#define O_FLG   26886144u     // 2048: cntA@mt*64, cntB@512+mt*64, xcnt@1024
#define O_BA    26888192u     // bufA[3] = 3*1048576  (slot0 zeroed = h_a(-1))
#define O_BB    30033920u     // bufB[3] = 3*1048576  (slot0 zeroed = h_b(-1))
#define WS_NEED 33179648u

extern "C" void kernel_launch(void* const* d_in, const int* in_sizes, int n_in,
                              void* d_out, int out_size, void* d_ws, size_t ws_size,
                              hipStream_t stream) {
    const float* x   = (const float*)d_in[0];
    const float* Wi0 = (const float*)d_in[1];
    const float* Wh0 = (const float*)d_in[2];
    const float* b0  = (const float*)d_in[3];
    const float* Wi1 = (const float*)d_in[4];
    const float* Wh1 = (const float*)d_in[5];
    const float* b1  = (const float*)d_in[6];
    const float* Wfc = (const float*)d_in[7];
    const float* bfc = (const float*)d_in[8];
    float* out = (float*)d_out;
    char*  ws  = (char*)d_ws;
    if (ws_size < WS_NEED) return;

    __bf16* W0p  = (__bf16*)(ws + O_W0P);
    __bf16* W1p  = (__bf16*)(ws + O_W1P);
    __bf16* Wfcp = (__bf16*)(ws + O_WFCP);
    float*  Wi0p = (float*)(ws + O_WI0P);
    float*  b1p  = (float*)(ws + O_B1P);
    char*   flg  = (char*)(ws + O_FLG);
    __bf16* bufA = (__bf16*)(ws + O_BA);
    __bf16* bufB = (__bf16*)(ws + O_BB);

    // zero flags + bufA slot0 (contiguous), and bufB slot0
    hipMemsetAsync(ws + O_FLG, 0, 2048u + 1048576u, stream);
    hipMemsetAsync(ws + O_BB, 0, 1048576u, stream);

    prep_w0   <<<4096, 256, 0, stream>>>(Wh0, W0p);
    prep_w1   <<<8192, 256, 0, stream>>>(Wi1, Wh1, W1p);
    prep_wfc  <<<768,  256, 0, stream>>>(Wfc, Wfcp);
    prep_small<<<16,   256, 0, stream>>>(Wi0, b0, b1, Wi0p, b1p);

    lstm_persist<<<256, 512, 0, stream>>>(x, W0p, W1p, Wfcp, Wi0p, b1p, bfc,
                                          bufA, bufB, flg, out);
}